// Round 18
// baseline (87.890 us; speedup 1.0000x reference)
//
#include <hip/hip_runtime.h>

// ChebGraphConv as ONE flat GEMM (K=192) over contiguous rows r = bt*1024+n:
//   out[r][o] = sum_{k,c} (d_k[n(r)] * x[r][c]) * Theta[k][c][o] + sum_k bias[k][o]
// R18 = R17 + DENSE-NORMAL stores via xs-buffer recycling (the one untested
// store quadrant: scattered-NT 85us / scattered-normal 90 / dense-NT 122 /
// dense-normal = THIS). Mechanism:
//   BODY(T) holds acc in regs one slot; after the next barrier WOUT(T)
//   ds_writes biased acc into xs[T&3] (just consumed; free until STAGE(T+4);
//   all waves' BODY(T) reads completed at the barrier). EPILOG(T) one slot
//   later reads 4-row-dense spans back (XOR-swizzle, bijective per 256B row)
//   and stores 2x contiguous 1KB per wave = FULL 128B lines, normal
//   write-back -> WRITE ~197MB with no partial-line RFO and no NT inflation.
//   STAGE-vs-EPILOG same-buffer reuse is wave-private (wave w stages exactly
//   the rows its EPILOG reads) -> in-wave issue order protects it.
// All waits include lgkmcnt(0) (outb crosses waves through LDS).
// vmcnt: {2,2,2,4,4,4,4,4,2} + lgkm-only tail drains.
// B=32,T=24,N=1024 -> 786432 rows. C_IN=C_OUT=64, K_cheb=3.

#define NNODES 1024
#define TILE_ROWS 64
#define NT 8
#define ROWS_PER_BLOCK (TILE_ROWS * NT)         // 512
#define NBLOCKS (786432 / ROWS_PER_BLOCK)       // 1536

// ws layout
#define WS_W  0                  // 24 frags * 64 lanes * 16B = 24 KB (bf16)
#define WS_BS (24 * 1024)        // 64 * f32 summed bias
#define WS_DV (24 * 1024 + 256)  // 1024 * f32x4 {d0,d1,d2,0}

typedef __attribute__((ext_vector_type(8))) short short8;  // 8 x bf16 MFMA frag
typedef __attribute__((ext_vector_type(4))) float f32x4;   // MFMA C/D frag
typedef __attribute__((ext_vector_type(4))) int   i32x4;

__device__ __forceinline__ unsigned short f2bf(float f) {
    union { float f; unsigned u; } v; v.f = f;
    unsigned r = v.u + 0x7FFFu + ((v.u >> 16) & 1u);
    return (unsigned short)(r >> 16);
}

__device__ __forceinline__ int cvt_pk_bf16(float lo, float hi) {
    int r;
    asm("v_cvt_pk_bf16_f32 %0, %1, %2" : "=v"(r) : "v"(lo), "v"(hi));
    return r;
}

__device__ __forceinline__ void gload_lds16(const void* g, void* l) {
    __builtin_amdgcn_global_load_lds(
        (const __attribute__((address_space(1))) void*)g,
        (__attribute__((address_space(3))) void*)l,
        16, 0, 0);
}

__global__ void cheb_prep(const float* __restrict__ Tks,
                          const float* __restrict__ Theta,
                          const float* __restrict__ bias,
                          unsigned char* __restrict__ ws) {
    const int b = blockIdx.x;
    const int l = threadIdx.x;   // 64 threads
    if (b < 24) {
        const int kc = b >> 3, h = (b >> 2) & 1, nb = b & 3;
        const int o  = nb * 16 + (l & 15);
        const int cb = h * 32 + (l >> 4) * 8;
        unsigned short* dst = (unsigned short*)(ws + WS_W) + ((size_t)b * 64 + l) * 8;
        #pragma unroll
        for (int j = 0; j < 8; ++j)
            dst[j] = f2bf(Theta[kc * 4096 + (cb + j) * 64 + o]);
    } else if (b < 40) {
        const int n = (b - 24) * 64 + l;
        const size_t dg = (size_t)n * (NNODES + 1);
        f32x4 v;
        v[0] = Tks[dg];
        v[1] = Tks[(size_t)NNODES * NNODES + dg];
        v[2] = Tks[(size_t)2 * NNODES * NNODES + dg];
        v[3] = 0.0f;
        *((f32x4*)(ws + WS_DV) + n) = v;
    } else {
        float* bs = (float*)(ws + WS_BS);
        bs[l] = bias[l] + bias[64 + l] + bias[128 + l];
    }
}

__global__ __launch_bounds__(512, 4) void cheb_main(
    const float* __restrict__ x,          // [786432 * 64]
    const unsigned char* __restrict__ ws,
    float* __restrict__ out)              // [786432 * 64]
{
    __shared__ float xs[4][TILE_ROWS * 64];   // 4 x 16 KB (x tiles, recycled as outb)
    __shared__ __align__(16) float dvs[ROWS_PER_BLOCK][4];  // 8 KB diag scales

    const int tid  = threadIdx.x;
    const int wave = tid >> 6;    // 0..7
    const int lane = tid & 63;
    const int lrow = lane & 15;
    const int lgrp = lane >> 4;
    const int wr   = wave >> 1;   // pair 0..3 (rows wr*16..+15)
    const int q    = wave & 1;    // o-half
    const size_t rowbase = (size_t)blockIdx.x * ROWS_PER_BLOCK;

    const unsigned short* wimg = (const unsigned short*)(ws + WS_W);
    const float*          bsum = (const float*)(ws + WS_BS);
    const f32x4*          dvec = (const f32x4*)(ws + WS_DV);

    short8 wf[3][2][2];                   // 12 W-frags for this o-half
    #pragma unroll
    for (int kc = 0; kc < 3; ++kc)
        #pragma unroll
        for (int h = 0; h < 2; ++h)
            #pragma unroll
            for (int nb = 0; nb < 2; ++nb)
                wf[kc][h][nb] = *(const short8*)(
                    wimg + ((size_t)(((kc * 2 + h) * 4 + q * 2 + nb) * 64 + lane)) * 8);

    f32x4 bs4[2];
    #pragma unroll
    for (int nb = 0; nb < 2; ++nb)
        bs4[nb] = *(const f32x4*)(bsum + q * 32 + nb * 16 + lgrp * 4);

    gload_lds16((const char*)dvec + (((rowbase + wave * 64) & (NNODES - 1)) * 16 + lane * 16),
                &dvs[wave * 64][0]);

#define STAGE(T) do { if ((T) < NT) {                                         \
        _Pragma("unroll")                                                     \
        for (int s = 0; s < 2; ++s) {                                         \
            const int u_ = wave * 2 + s;                                      \
            const int R_ = u_ * 4 + lgrp;                                     \
            const int c_ = (lrow * 16) ^ ((R_ & 7) << 4);                     \
            const char* g_ = (const char*)x +                                 \
                (((rowbase + (size_t)(T) * TILE_ROWS + R_) << 8) + c_);       \
            gload_lds16(g_, (char*)&xs[(T) & 3][0] + u_ * 1024);              \
        } } } while (0)

#define WAITV(N) do {                                                         \
        asm volatile("s_waitcnt vmcnt(" #N ") lgkmcnt(0)" ::: "memory");      \
        __builtin_amdgcn_sched_barrier(0);                                    \
        __builtin_amdgcn_s_barrier();                                         \
        __builtin_amdgcn_sched_barrier(0);                                    \
    } while (0)

#define WAITL() do {                                                          \
        asm volatile("s_waitcnt lgkmcnt(0)" ::: "memory");                    \
        __builtin_amdgcn_sched_barrier(0);                                    \
        __builtin_amdgcn_s_barrier();                                         \
        __builtin_amdgcn_sched_barrier(0);                                    \
    } while (0)

    // compute acc for tile T into named regs (held one slot)
#define BODY(T, A0, A1) do {                                                  \
        const int m_ = (lrow & 7) << 4;                                       \
        const char* rowp = (const char*)&xs[(T) & 3][0]                       \
                         + (wr * 16 + lrow) * 256;                            \
        const int c00 = (lgrp * 32) ^ m_;                                     \
        const int c01 = (lgrp * 32 + 16) ^ m_;                                \
        const f32x4 x0 = *(const f32x4*)(rowp + c00);                         \
        const f32x4 x1 = *(const f32x4*)(rowp + c01);                         \
        const f32x4 x2 = *(const f32x4*)(rowp + 128 + c00);                   \
        const f32x4 x3 = *(const f32x4*)(rowp + 128 + c01);                   \
        const f32x4 dv = *(const f32x4*)(&dvs[(T) * TILE_ROWS                 \
                                              + wr * 16 + lrow][0]);          \
        short8 xf[3][2];                                                      \
        _Pragma("unroll")                                                     \
        for (int kc = 0; kc < 3; ++kc) {                                      \
            const float dk = dv[kc];                                          \
            i32x4 r0, r1;                                                     \
            r0[0] = cvt_pk_bf16(dk * x0[0], dk * x0[1]);                      \
            r0[1] = cvt_pk_bf16(dk * x0[2], dk * x0[3]);                      \
            r0[2] = cvt_pk_bf16(dk * x1[0], dk * x1[1]);                      \
            r0[3] = cvt_pk_bf16(dk * x1[2], dk * x1[3]);                      \
            r1[0] = cvt_pk_bf16(dk * x2[0], dk * x2[1]);                      \
            r1[1] = cvt_pk_bf16(dk * x2[2], dk * x2[3]);                      \
            r1[2] = cvt_pk_bf16(dk * x3[0], dk * x3[1]);                      \
            r1[3] = cvt_pk_bf16(dk * x3[2], dk * x3[3]);                      \
            xf[kc][0] = __builtin_bit_cast(short8, r0);                       \
            xf[kc][1] = __builtin_bit_cast(short8, r1);                       \
        }                                                                     \
        A0 = f32x4{0,0,0,0}; A1 = f32x4{0,0,0,0};                             \
        __builtin_amdgcn_s_setprio(1);                                        \
        _Pragma("unroll")                                                     \
        for (int kc = 0; kc < 3; ++kc)                                        \
            _Pragma("unroll")                                                 \
            for (int h = 0; h < 2; ++h) {                                     \
                A0 = __builtin_amdgcn_mfma_f32_16x16x32_bf16(                 \
                         wf[kc][h][0], xf[kc][h], A0, 0, 0, 0);               \
                A1 = __builtin_amdgcn_mfma_f32_16x16x32_bf16(                 \
                         wf[kc][h][1], xf[kc][h], A1, 0, 0, 0);               \
            }                                                                 \
        __builtin_amdgcn_s_setprio(0);                                        \
    } while (0)

    // ds_write biased acc(T) into xs[T&3] pair region (dense row layout,
    // per-row XOR swizzle; bijective: {q,nb,lgrp} enumerate bytes 0..240)
#define WOUT(T, A0, A1) do {                                                  \
        char* pb = (char*)&xs[(T) & 3][0] + wr * 4096 + lrow * 256;           \
        const int sw = (lrow & 7) << 4;                                       \
        f32x4 o0, o1;                                                         \
        _Pragma("unroll")                                                     \
        for (int j = 0; j < 4; ++j) { o0[j] = A0[j] + bs4[0][j];              \
                                      o1[j] = A1[j] + bs4[1][j]; }            \
        *(f32x4*)(pb + ((q * 128 + 0  + lgrp * 16) ^ sw)) = o0;               \
        *(f32x4*)(pb + ((q * 128 + 64 + lgrp * 16) ^ sw)) = o1;               \
    } while (0)

    // read 8 dense rows back, store as 2x contiguous 1KB (full 128B lines)
#define EPILOG(T) do {                                                        \
        _Pragma("unroll")                                                     \
        for (int s = 0; s < 2; ++s) {                                         \
            const int row = q * 8 + s * 4 + lgrp;                             \
            const f32x4 v = *(const f32x4*)((const char*)&xs[(T) & 3][0]      \
                + wr * 4096 + row * 256 + ((lrow * 16) ^ ((row & 7) << 4)));  \
            *(f32x4*)(out + (rowbase + (size_t)(T) * TILE_ROWS + wr * 16      \
                             + row) * 64 + lrow * 4) = v;                     \
        } } while (0)

    f32x4 accA0, accA1, accB0, accB1;

    STAGE(0); STAGE(1);
    WAITV(2);            STAGE(2);            BODY(0, accA0, accA1);
    WAITV(2);            STAGE(3); WOUT(0, accA0, accA1); BODY(1, accB0, accB1);
    WAITV(2); EPILOG(0); STAGE(4); WOUT(1, accB0, accB1); BODY(2, accA0, accA1);
    WAITV(4); EPILOG(1); STAGE(5); WOUT(2, accA0, accA1); BODY(3, accB0, accB1);
    WAITV(4); EPILOG(2); STAGE(6); WOUT(3, accB0, accB1); BODY(4, accA0, accA1);
    WAITV(4); EPILOG(3); STAGE(7); WOUT(4, accA0, accA1); BODY(5, accB0, accB1);
    WAITV(4); EPILOG(4);           WOUT(5, accB0, accB1); BODY(6, accA0, accA1);
    WAITV(2); EPILOG(5);           WOUT(6, accA0, accA1); BODY(7, accB0, accB1);
    WAITL();  EPILOG(6);           WOUT(7, accB0, accB1);
    WAITL();  EPILOG(7);

#undef STAGE
#undef WAITV
#undef WAITL
#undef BODY
#undef WOUT
#undef EPILOG
}

extern "C" void kernel_launch(void* const* d_in, const int* in_sizes, int n_in,
                              void* d_out, int out_size, void* d_ws, size_t ws_size,
                              hipStream_t stream) {
    const float* x     = (const float*)d_in[0];
    const float* Tks   = (const float*)d_in[1];
    const float* Theta = (const float*)d_in[2];
    const float* bias  = (const float*)d_in[3];
    float* out = (float*)d_out;
    unsigned char* ws = (unsigned char*)d_ws;

    hipLaunchKernelGGL(cheb_prep, dim3(41), dim3(64), 0, stream,
                       Tks, Theta, bias, ws);
    hipLaunchKernelGGL(cheb_main, dim3(NBLOCKS), dim3(512), 0, stream,
                       x, ws, out);
}

// Round 19
// 85.644 us; speedup vs baseline: 1.0262x; 1.0262x over previous
//
#include <hip/hip_runtime.h>

// ChebGraphConv as ONE flat GEMM (K=192) over contiguous rows r = bt*1024+n:
//   out[r][o] = sum_{k,c} (d_k[n(r)] * x[r][c]) * Theta[k][c][o] + sum_k bias[k][o]
// FINAL (= R10/R17, best of 19 rounds: 85.2us, ~4.5 TB/s effective HBM on the
// mixed read+write stream -- the measured practical ceiling for this op).
// Structure:
//  - 8-wave (512-thr) blocks; wave (wr,q) computes 16 rows x 32 o-cols,
//    holding 12 W-frags (48 VGPR) -> VGPR 56 total, 2 blocks/CU
//  - x staged via global_load_lds width-16 (dense 1KB/instr), source
//    pre-swizzled (col ^= (row&7)<<4) for conflict-free swizzled ds_read_b128
//  - 4 LDS x-buffers, depth-3 stage-ahead, counted vmcnt(N) + s_barrier
//    (N never 0 in steady state: {2,4,6,6,6,6,6,4})
//  - s_setprio(1) around the MFMA cluster
//  - NON-TEMPORAL scattered dwordx4 stores (store-path matrix measured:
//    scattered-NT 85.2 / scattered-normal 89.6 / dense-NT 122 / dense-normal
//    87.9 -- NT bypasses the slow partial-line L2 merge path and wins despite
//    +37% write bytes)
// B=32,T=24,N=1024 -> 786432 rows. C_IN=C_OUT=64, K_cheb=3.

#define NNODES 1024
#define TILE_ROWS 64
#define NT 8
#define ROWS_PER_BLOCK (TILE_ROWS * NT)         // 512
#define NBLOCKS (786432 / ROWS_PER_BLOCK)       // 1536

// ws layout
#define WS_W  0                  // 24 frags * 64 lanes * 16B = 24 KB (bf16)
#define WS_BS (24 * 1024)        // 64 * f32 summed bias
#define WS_DV (24 * 1024 + 256)  // 1024 * f32x4 {d0,d1,d2,0}

typedef __attribute__((ext_vector_type(8))) short short8;  // 8 x bf16 MFMA frag
typedef __attribute__((ext_vector_type(4))) float f32x4;   // MFMA C/D frag
typedef __attribute__((ext_vector_type(4))) int   i32x4;

// round-to-nearest-even f32 -> bf16 bits (prep kernel only)
__device__ __forceinline__ unsigned short f2bf(float f) {
    union { float f; unsigned u; } v; v.f = f;
    unsigned r = v.u + 0x7FFFu + ((v.u >> 16) & 1u);
    return (unsigned short)(r >> 16);
}

// pack 2 f32 -> 2 bf16 in one VALU op
__device__ __forceinline__ int cvt_pk_bf16(float lo, float hi) {
    int r;
    asm("v_cvt_pk_bf16_f32 %0, %1, %2" : "=v"(r) : "v"(lo), "v"(hi));
    return r;
}

// dense global->LDS: wave-uniform LDS base, lane l lands at base + l*16
__device__ __forceinline__ void gload_lds16(const void* g, void* l) {
    __builtin_amdgcn_global_load_lds(
        (const __attribute__((address_space(1))) void*)g,
        (__attribute__((address_space(3))) void*)l,
        16, 0, 0);
}

__global__ void cheb_prep(const float* __restrict__ Tks,
                          const float* __restrict__ Theta,
                          const float* __restrict__ bias,
                          unsigned char* __restrict__ ws) {
    const int b = blockIdx.x;
    const int l = threadIdx.x;   // 64 threads
    if (b < 24) {
        // frag f = (kc*2+h)*4 + nb ; lane l holds W^T row o = nb*16+(l&15),
        // k-slice c = h*32 + (l>>4)*8 + j  (A-operand layout, 16x16x32)
        const int kc = b >> 3, h = (b >> 2) & 1, nb = b & 3;
        const int o  = nb * 16 + (l & 15);
        const int cb = h * 32 + (l >> 4) * 8;
        unsigned short* dst = (unsigned short*)(ws + WS_W) + ((size_t)b * 64 + l) * 8;
        #pragma unroll
        for (int j = 0; j < 8; ++j)
            dst[j] = f2bf(Theta[kc * 4096 + (cb + j) * 64 + o]);
    } else if (b < 40) {
        const int n = (b - 24) * 64 + l;
        const size_t dg = (size_t)n * (NNODES + 1);
        f32x4 v;
        v[0] = Tks[dg];
        v[1] = Tks[(size_t)NNODES * NNODES + dg];
        v[2] = Tks[(size_t)2 * NNODES * NNODES + dg];
        v[3] = 0.0f;
        *((f32x4*)(ws + WS_DV) + n) = v;
    } else {
        float* bs = (float*)(ws + WS_BS);
        bs[l] = bias[l] + bias[64 + l] + bias[128 + l];
    }
}

__global__ __launch_bounds__(512, 4) void cheb_main(
    const float* __restrict__ x,          // [786432 * 64]
    const unsigned char* __restrict__ ws,
    float* __restrict__ out)              // [786432 * 64]
{
    __shared__ float xs[4][TILE_ROWS * 64];   // 4 x 16 KB swizzled x tiles
    __shared__ __align__(16) float dvs[ROWS_PER_BLOCK][4];  // 8 KB diag scales

    const int tid  = threadIdx.x;
    const int wave = tid >> 6;    // 0..7
    const int lane = tid & 63;
    const int lrow = lane & 15;
    const int lgrp = lane >> 4;
    const int wr   = wave >> 1;   // row-group 0..3
    const int q    = wave & 1;    // o-half
    const size_t rowbase = (size_t)blockIdx.x * ROWS_PER_BLOCK;

    const unsigned short* wimg = (const unsigned short*)(ws + WS_W);
    const float*          bsum = (const float*)(ws + WS_BS);
    const f32x4*          dvec = (const f32x4*)(ws + WS_DV);

    // ---- prologue: all vmem here is OLDER than stage(0) -> never affects N ----
    short8 wf[3][2][2];                   // 12 W-frags for this o-half (48 VGPR)
    #pragma unroll
    for (int kc = 0; kc < 3; ++kc)
        #pragma unroll
        for (int h = 0; h < 2; ++h)
            #pragma unroll
            for (int nb = 0; nb < 2; ++nb)
                wf[kc][h][nb] = *(const short8*)(
                    wimg + ((size_t)(((kc * 2 + h) * 4 + q * 2 + nb) * 64 + lane)) * 8);

    f32x4 bs4[2];
    #pragma unroll
    for (int nb = 0; nb < 2; ++nb)
        bs4[nb] = *(const f32x4*)(bsum + q * 32 + nb * 16 + lgrp * 4);

    // stage diag scales: wave w -> rows 64w..64w+63 (wave-private 1KB chunk)
    gload_lds16((const char*)dvec + (((rowbase + wave * 64) & (NNODES - 1)) * 16 + lane * 16),
                &dvs[wave * 64][0]);

    // ---- STAGE tile T: 16 x 1KB chunks; wave stages chunks 2w,2w+1 ----
    // chunk u covers tile rows 4u..4u+3; lane l -> LDS byte u*1024 + l*16
    // = row (4u + l>>4), linear col (l&15)*16; source col ^= ((row&7)<<4)
#define STAGE(T) do { if ((T) < NT) {                                         \
        _Pragma("unroll")                                                     \
        for (int s = 0; s < 2; ++s) {                                         \
            const int u_ = wave * 2 + s;                                      \
            const int R_ = u_ * 4 + lgrp;                                     \
            const int c_ = (lrow * 16) ^ ((R_ & 7) << 4);                     \
            const char* g_ = (const char*)x +                                 \
                (((rowbase + (size_t)(T) * TILE_ROWS + R_) << 8) + c_);       \
            gload_lds16(g_, (char*)&xs[(T) & 3][0] + u_ * 1024);              \
        } } } while (0)

#define WAITV(N) do {                                                         \
        asm volatile("s_waitcnt vmcnt(" #N ")" ::: "memory");                 \
        __builtin_amdgcn_sched_barrier(0);                                    \
        __builtin_amdgcn_s_barrier();                                         \
        __builtin_amdgcn_sched_barrier(0);                                    \
    } while (0)

#define BODY(T) do {                                                          \
        const int m_ = (lrow & 7) << 4;                                       \
        const char* rowp = (const char*)&xs[(T) & 3][0]                       \
                         + (wr * 16 + lrow) * 256;                            \
        const int c00 = (lgrp * 32) ^ m_;                                     \
        const int c01 = (lgrp * 32 + 16) ^ m_;                                \
        const f32x4 x0 = *(const f32x4*)(rowp + c00);                         \
        const f32x4 x1 = *(const f32x4*)(rowp + c01);                         \
        const f32x4 x2 = *(const f32x4*)(rowp + 128 + c00);                   \
        const f32x4 x3 = *(const f32x4*)(rowp + 128 + c01);                   \
        const f32x4 dv = *(const f32x4*)(&dvs[(T) * TILE_ROWS                 \
                                              + wr * 16 + lrow][0]);          \
        short8 xf[3][2];                                                      \
        _Pragma("unroll")                                                     \
        for (int kc = 0; kc < 3; ++kc) {                                      \
            const float dk = dv[kc];                                          \
            i32x4 r0, r1;                                                     \
            r0[0] = cvt_pk_bf16(dk * x0[0], dk * x0[1]);                      \
            r0[1] = cvt_pk_bf16(dk * x0[2], dk * x0[3]);                      \
            r0[2] = cvt_pk_bf16(dk * x1[0], dk * x1[1]);                      \
            r0[3] = cvt_pk_bf16(dk * x1[2], dk * x1[3]);                      \
            r1[0] = cvt_pk_bf16(dk * x2[0], dk * x2[1]);                      \
            r1[1] = cvt_pk_bf16(dk * x2[2], dk * x2[3]);                      \
            r1[2] = cvt_pk_bf16(dk * x3[0], dk * x3[1]);                      \
            r1[3] = cvt_pk_bf16(dk * x3[2], dk * x3[3]);                      \
            xf[kc][0] = __builtin_bit_cast(short8, r0);                       \
            xf[kc][1] = __builtin_bit_cast(short8, r1);                       \
        }                                                                     \
        f32x4 acc[2] = {f32x4{0,0,0,0}, f32x4{0,0,0,0}};                      \
        __builtin_amdgcn_s_setprio(1);                                        \
        _Pragma("unroll")                                                     \
        for (int kc = 0; kc < 3; ++kc)                                        \
            _Pragma("unroll")                                                 \
            for (int h = 0; h < 2; ++h)                                       \
                _Pragma("unroll")                                             \
                for (int nb = 0; nb < 2; ++nb)                                \
                    acc[nb] = __builtin_amdgcn_mfma_f32_16x16x32_bf16(        \
                        wf[kc][h][nb], xf[kc][h], acc[nb], 0, 0, 0);          \
        __builtin_amdgcn_s_setprio(0);                                        \
        float* orow = out + (rowbase + (size_t)(T) * TILE_ROWS                \
                           + wr * 16 + lrow) * 64 + q * 32;                   \
        _Pragma("unroll")                                                     \
        for (int nb = 0; nb < 2; ++nb) {                                      \
            f32x4 o4;                                                         \
            _Pragma("unroll")                                                 \
            for (int j = 0; j < 4; ++j) o4[j] = acc[nb][j] + bs4[nb][j];      \
            __builtin_nontemporal_store(o4, (f32x4*)(orow + nb * 16 + lgrp * 4)); \
        }                                                                     \
    } while (0)

    // ---- pipeline: depth-3 stage-ahead, 4 buffers ----
    // exact queue (2 stage-loads + 2 nt-stores per iter): N={4,6,8,...,8,6};
    // -2 safety margin -> {2,4,6,6,6,6,6,4}
    STAGE(0); STAGE(1); STAGE(2);
    WAITV(2); STAGE(3);  BODY(0);
    WAITV(4); STAGE(4);  BODY(1);
    WAITV(6); STAGE(5);  BODY(2);
    WAITV(6); STAGE(6);  BODY(3);
    WAITV(6); STAGE(7);  BODY(4);
    WAITV(6); STAGE(8);  BODY(5);   // STAGE(8..10) compile out
    WAITV(6); STAGE(9);  BODY(6);
    WAITV(4); STAGE(10); BODY(7);

#undef STAGE
#undef WAITV
#undef BODY
}

extern "C" void kernel_launch(void* const* d_in, const int* in_sizes, int n_in,
                              void* d_out, int out_size, void* d_ws, size_t ws_size,
                              hipStream_t stream) {
    const float* x     = (const float*)d_in[0];
    const float* Tks   = (const float*)d_in[1];
    const float* Theta = (const float*)d_in[2];
    const float* bias  = (const float*)d_in[3];
    float* out = (float*)d_out;
    unsigned char* ws = (unsigned char*)d_ws;

    hipLaunchKernelGGL(cheb_prep, dim3(41), dim3(64), 0, stream,
                       Tks, Theta, bias, ws);
    hipLaunchKernelGGL(cheb_main, dim3(NBLOCKS), dim3(512), 0, stream,
                       x, ws, out);
}